// Round 1
// baseline (2500.097 us; speedup 1.0000x reference)
//
#include <hip/hip_runtime.h>

// ---------------------------------------------------------------------------
// Bidirectional GRU encoder, MI355X (gfx950)
//   src (512,64,1024) f32 -> outputs (512,64,256) f32, hidden (1,64,256) f32
// Plan:
//   prep    : convert Wih/Whh/Wout/Whid to bf16 in ws
//   gemm_gx : gx[d] = src @ Wih_d.T + bih_d   (bf16 MFMA, 128x256 tiles)
//   recur   : 8 WGs (2 dir x 4 batch-slices of 16 rows). Whh persistent in
//             VGPRs (192/wave), h in LDS (bf16, swizzled), state fp32 in regs.
//   gemm_out: outputs = [out_f|out_b] @ Wout.T + bout
//   hidden_k: hidden = tanh([h_f|h_b] @ Whid.T + bhid)
// ---------------------------------------------------------------------------

typedef short    bf16x8 __attribute__((ext_vector_type(8)));   // 8 bf16 = 4 VGPR
typedef float    f32x4  __attribute__((ext_vector_type(4)));
typedef float    f32x16 __attribute__((ext_vector_type(16)));

union U16x8 { uint4 u4; bf16x8 b; };

__device__ __forceinline__ unsigned short f2bf(float f) {
  unsigned int u = __builtin_bit_cast(unsigned int, f);
  u += 0x7fffu + ((u >> 16) & 1u);           // RNE
  return (unsigned short)(u >> 16);
}
__device__ __forceinline__ float bf2f(unsigned short h) {
  unsigned int u = ((unsigned int)h) << 16;
  return __builtin_bit_cast(float, u);
}
__device__ __forceinline__ float fast_rcp(float x) { return __builtin_amdgcn_rcpf(x); }
__device__ __forceinline__ float sigf(float x) { return fast_rcp(1.f + __expf(-x)); }
__device__ __forceinline__ float tanh_fast(float x) {
  float e = __expf(2.f * x);
  return 1.f - 2.f * fast_rcp(e + 1.f);
}

// ws element (u16) offsets
#define WS_GX      ((size_t)0)          // 2 * 512*64*768 = 50331648
#define WS_OUT     ((size_t)50331648)   // 2 * 512*64*256 = 16777216
#define WS_WIH     ((size_t)67108864)   // 2 * 768*1024   = 1572864
#define WS_WHH     ((size_t)68681728)   // 2 * 768*256    = 393216
#define WS_WOUT    ((size_t)69074944)   // 256*512        = 131072
#define WS_WHID    ((size_t)69206016)   // 256*512        = 131072
#define WS_HFIN    ((size_t)69337088)   // 2 * 64*256     = 32768

// ---------------------------------------------------------------- prep ------
__global__ void prep_cvt(const float* __restrict__ wih_f, const float* __restrict__ wih_b,
                         const float* __restrict__ whh_f, const float* __restrict__ whh_b,
                         const float* __restrict__ wout,  const float* __restrict__ whid,
                         unsigned short* __restrict__ dwih, unsigned short* __restrict__ dwhh,
                         unsigned short* __restrict__ dwout, unsigned short* __restrict__ dwhid) {
  int i4 = blockIdx.x * 256 + threadIdx.x;   // one float4 each; grid exact
  const float* s; unsigned short* d;
  if      (i4 < 196608) { s = wih_f; d = dwih; }
  else if (i4 < 393216) { s = wih_b; d = dwih + 786432; i4 -= 196608; }
  else if (i4 < 442368) { s = whh_f; d = dwhh;          i4 -= 393216; }
  else if (i4 < 491520) { s = whh_b; d = dwhh + 196608; i4 -= 442368; }
  else if (i4 < 524288) { s = wout;  d = dwout;         i4 -= 491520; }
  else                  { s = whid;  d = dwhid;         i4 -= 524288; }
  float4 v = ((const float4*)s)[i4];
  ushort4 o; o.x = f2bf(v.x); o.y = f2bf(v.y); o.z = f2bf(v.z); o.w = f2bf(v.w);
  ((ushort4*)d)[i4] = o;
}

// -------------------------------------------------------------- gx GEMM -----
// C[m][cg] = sum_k src[m][k] * wih[cg][k] + bih ;  M=32768, K=1024, N=1536
// tile 128(M) x 256(N), BK=64, 8 waves (2x4 of 64x64), 32x32x16 MFMA
__global__ __launch_bounds__(512) void gemm_gx(
    const float* __restrict__ src, const unsigned short* __restrict__ wihbf,
    const float* __restrict__ bih_f, const float* __restrict__ bih_b,
    unsigned short* __restrict__ gx) {
  __shared__ char Ab[128 * 128];   // [128 rows][64 k] bf16, swizzled
  __shared__ char Bb[256 * 128];   // [256 n  ][64 k] bf16, swizzled

  const int bx = blockIdx.x;                  // 1536
  const int xcd = bx & 7, chunk = bx >> 3;    // XCD-contiguous mtile ownership
  const int mtile = xcd * 32 + chunk / 6;
  const int ntile = chunk % 6;

  const int tid = threadIdx.x;
  const int w = tid >> 6, l = tid & 63;
  const int l31 = l & 31, l5 = l >> 5;
  const int wr = w >> 2, wc = w & 3;

  f32x16 acc[2][2] = {};

  for (int ks = 0; ks < 16; ++ks) {
    // stage A (fp32 -> bf16), 128x64
#pragma unroll
    for (int i = 0; i < 4; ++i) {
      int cc = i * 512 + tid; int row = cc >> 4, c4 = cc & 15;
      float4 v = *(const float4*)(src + (size_t)(mtile * 128 + row) * 1024 + ks * 64 + c4 * 4);
      ushort4 o; o.x = f2bf(v.x); o.y = f2bf(v.y); o.z = f2bf(v.z); o.w = f2bf(v.w);
      *(ushort4*)(Ab + row * 128 + ((c4 * 8) ^ ((row & 7) << 4))) = o;
    }
    // stage B (bf16), 256x64 : Bb[n][k] = wih[ntile*256+n][ks*64+k]
#pragma unroll
    for (int i = 0; i < 4; ++i) {
      int cc = i * 512 + tid; int row = cc >> 3, c8 = cc & 7;
      uint4 v = *(const uint4*)(wihbf + (size_t)(ntile * 256 + row) * 1024 + ks * 64 + c8 * 8);
      *(uint4*)(Bb + row * 128 + ((c8 * 16) ^ ((row & 7) << 4))) = v;
    }
    __syncthreads();
#pragma unroll
    for (int kb = 0; kb < 4; ++kb) {
      const int kby = kb * 32 + l5 * 16;
      bf16x8 Af[2], Bf[2];
#pragma unroll
      for (int rt = 0; rt < 2; ++rt) {
        int row = wr * 64 + rt * 32 + l31;
        Af[rt] = *(const bf16x8*)(Ab + row * 128 + (kby ^ ((row & 7) << 4)));
      }
#pragma unroll
      for (int ct = 0; ct < 2; ++ct) {
        int nn = wc * 64 + ct * 32 + l31;
        Bf[ct] = *(const bf16x8*)(Bb + nn * 128 + (kby ^ ((nn & 7) << 4)));
      }
#pragma unroll
      for (int rt = 0; rt < 2; ++rt)
#pragma unroll
        for (int ct = 0; ct < 2; ++ct)
          acc[rt][ct] = __builtin_amdgcn_mfma_f32_32x32x16_bf16(Af[rt], Bf[ct], acc[rt][ct], 0, 0, 0);
    }
    __syncthreads();
  }

  const int cgbase = ntile * 256;
  const int d = cgbase >= 768;
  const float* bih = d ? bih_b : bih_f;
#pragma unroll
  for (int ct = 0; ct < 2; ++ct) {
    const int cg = cgbase + wc * 64 + ct * 32 + l31;
    const int c = cg - d * 768;
    const float bias = bih[c];
#pragma unroll
    for (int rt = 0; rt < 2; ++rt) {
#pragma unroll
      for (int r = 0; r < 16; ++r) {
        const int rr = (r & 3) + 8 * (r >> 2) + 4 * l5;
        const int m = mtile * 128 + wr * 64 + rt * 32 + rr;
        gx[(size_t)d * 25165824 + (size_t)m * 768 + c] = f2bf(acc[rt][ct][r] + bias);
      }
    }
  }
}

// ------------------------------------------------------------- recurrence ---
// 8 WGs: d = blk>>2, batch slice = (blk&3)*16. 8 waves; wave w owns gate
// columns [32w, 32w+32). Whh bf16 fragments persistent in VGPRs (192/wave).
__global__ __launch_bounds__(512, 2) void recur(
    const unsigned short* __restrict__ whhbf,
    const float* __restrict__ bhh_f, const float* __restrict__ bhh_b,
    const unsigned short* __restrict__ gx,
    unsigned short* __restrict__ outw,
    unsigned short* __restrict__ hfin) {
  __shared__ char hbuf[2][8192];     // [16 rows][256 cols] bf16, swizzled
  __shared__ char gxbuf[24576];      // [16 rows][768 cols] bf16, linear

  const int tid = threadIdx.x;
  const int w = tid >> 6, l = tid & 63;
  const int l15 = l & 15, l4 = l >> 4;
  const int d = blockIdx.x >> 2;
  const int bsl = (blockIdx.x & 3) << 4;
  const float* bhh = d ? bhh_b : bhh_f;

  // persistent weight fragments: B[k][n] = Whh[n][k]
  bf16x8 Bw[6][8];
  float bhhv[6];
#pragma unroll
  for (int j = 0; j < 6; ++j) {
    const int g = j >> 1, jt = j & 1;
    const int n = g * 256 + w * 32 + jt * 16 + l15;
    bhhv[j] = bhh[n];
#pragma unroll
    for (int kb = 0; kb < 8; ++kb) {
      const int kel = kb * 32 + l4 * 8;
      U16x8 u;
      u.u4 = *(const uint4*)(whhbf + (size_t)d * 196608 + (size_t)n * 256 + kel);
      Bw[j][kb] = u.b;
    }
  }

  {
    uint4 zz; zz.x = 0u; zz.y = 0u; zz.z = 0u; zz.w = 0u;
    *(uint4*)(hbuf[0] + tid * 16) = zz;     // h0 = 0
  }
  float hown[2][4] = {{0.f, 0.f, 0.f, 0.f}, {0.f, 0.f, 0.f, 0.f}};
  __syncthreads();

  const unsigned short* gxd = gx + (size_t)d * 25165824 + (size_t)bsl * 768;
  unsigned short* outd = outw + (size_t)d * 8388608;

  int cur = 0;
  for (int s = 0; s < 512; ++s) {
    const int tt = d ? (511 - s) : s;

    // issue gx tile loads early (16 rows x 768 bf16, contiguous 24576 B)
    const uint4* gsrc = (const uint4*)(gxd + (size_t)tt * 49152);
    uint4 g0 = gsrc[tid], g1 = gsrc[tid + 512], g2 = gsrc[tid + 1024];

    f32x4 acc[6];
#pragma unroll
    for (int j = 0; j < 6; ++j) { acc[j][0] = bhhv[j]; acc[j][1] = bhhv[j]; acc[j][2] = bhhv[j]; acc[j][3] = bhhv[j]; }

    // gh = h @ Whh.T  (A from LDS, B persistent)
    {
      const char* hb = hbuf[cur];
      const int row = l15;
      const int sw = (row & 7) << 4;
#pragma unroll
      for (int kb = 0; kb < 8; ++kb) {
        bf16x8 Af = *(const bf16x8*)(hb + row * 512 + ((kb * 64 + l4 * 16) ^ sw));
#pragma unroll
        for (int j = 0; j < 6; ++j)
          acc[j] = __builtin_amdgcn_mfma_f32_16x16x32_bf16(Af, Bw[j][kb], acc[j], 0, 0, 0);
      }
    }

    // land gx tile into LDS
    ((uint4*)gxbuf)[tid] = g0;
    ((uint4*)gxbuf)[tid + 512] = g1;
    ((uint4*)gxbuf)[tid + 1024] = g2;
    __syncthreads();

    // gates + state update
    char* hbn = hbuf[cur ^ 1];
    const unsigned short* gxb = (const unsigned short*)gxbuf;
#pragma unroll
    for (int jt = 0; jt < 2; ++jt) {
      const int col = w * 32 + jt * 16 + l15;
#pragma unroll
      for (int q = 0; q < 4; ++q) {
        const int row = l4 * 4 + q;
        const float gxr = bf2f(gxb[row * 768 + col]);
        const float gxz = bf2f(gxb[row * 768 + col + 256]);
        const float gxn = bf2f(gxb[row * 768 + col + 512]);
        const float rg = sigf(gxr + acc[jt][q]);
        const float zg = sigf(gxz + acc[2 + jt][q]);
        const float ng = tanh_fast(gxn + rg * acc[4 + jt][q]);
        const float hn = (1.f - zg) * ng + zg * hown[jt][q];
        hown[jt][q] = hn;
        const unsigned short h16 = f2bf(hn);
        *(unsigned short*)(hbn + row * 512 + ((col * 2) ^ ((row & 7) << 4))) = h16;
        outd[((size_t)tt * 64 + bsl + row) * 256 + col] = h16;
      }
    }
    __syncthreads();
    cur ^= 1;
  }

#pragma unroll
  for (int jt = 0; jt < 2; ++jt) {
    const int col = w * 32 + jt * 16 + l15;
#pragma unroll
    for (int q = 0; q < 4; ++q) {
      const int row = l4 * 4 + q;
      hfin[(size_t)d * 16384 + (size_t)(bsl + row) * 256 + col] = f2bf(hown[jt][q]);
    }
  }
}

// ------------------------------------------------------------ out proj ------
// out[m][n] = [out_f|out_b][m][:] @ Wout.T + bout ; M=32768, K=512, N=256
__global__ __launch_bounds__(256) void gemm_out(
    const unsigned short* __restrict__ outws, const unsigned short* __restrict__ woutbf,
    const float* __restrict__ bout, float* __restrict__ out) {
  __shared__ char Ab[128 * 128];
  __shared__ char Bb[128 * 128];
  const int mtile = blockIdx.x, ntile = blockIdx.y;
  const int tid = threadIdx.x;
  const int w = tid >> 6, l = tid & 63;
  const int l31 = l & 31, l5 = l >> 5;
  const int wr = w >> 1, wc = w & 1;

  f32x16 acc[2][2] = {};

  for (int ks = 0; ks < 8; ++ks) {
    const unsigned short* asrc = outws + (size_t)(ks >> 2) * 8388608;
    const int k0 = (ks & 3) * 64;
#pragma unroll
    for (int i = 0; i < 4; ++i) {
      int cc = i * 256 + tid; int row = cc >> 3, c8 = cc & 7;
      uint4 v = *(const uint4*)(asrc + (size_t)(mtile * 128 + row) * 256 + k0 + c8 * 8);
      *(uint4*)(Ab + row * 128 + ((c8 * 16) ^ ((row & 7) << 4))) = v;
    }
#pragma unroll
    for (int i = 0; i < 4; ++i) {
      int cc = i * 256 + tid; int row = cc >> 3, c8 = cc & 7;
      uint4 v = *(const uint4*)(woutbf + (size_t)(ntile * 128 + row) * 512 + ks * 64 + c8 * 8);
      *(uint4*)(Bb + row * 128 + ((c8 * 16) ^ ((row & 7) << 4))) = v;
    }
    __syncthreads();
#pragma unroll
    for (int kb = 0; kb < 4; ++kb) {
      const int kby = kb * 32 + l5 * 16;
      bf16x8 Af[2], Bf[2];
#pragma unroll
      for (int rt = 0; rt < 2; ++rt) {
        int row = wr * 64 + rt * 32 + l31;
        Af[rt] = *(const bf16x8*)(Ab + row * 128 + (kby ^ ((row & 7) << 4)));
      }
#pragma unroll
      for (int ct = 0; ct < 2; ++ct) {
        int nn = wc * 64 + ct * 32 + l31;
        Bf[ct] = *(const bf16x8*)(Bb + nn * 128 + (kby ^ ((nn & 7) << 4)));
      }
#pragma unroll
      for (int rt = 0; rt < 2; ++rt)
#pragma unroll
        for (int ct = 0; ct < 2; ++ct)
          acc[rt][ct] = __builtin_amdgcn_mfma_f32_32x32x16_bf16(Af[rt], Bf[ct], acc[rt][ct], 0, 0, 0);
    }
    __syncthreads();
  }

#pragma unroll
  for (int ct = 0; ct < 2; ++ct) {
    const int n = ntile * 128 + wc * 64 + ct * 32 + l31;
    const float bias = bout[n];
#pragma unroll
    for (int rt = 0; rt < 2; ++rt) {
#pragma unroll
      for (int r = 0; r < 16; ++r) {
        const int rr = (r & 3) + 8 * (r >> 2) + 4 * l5;
        const int m = mtile * 128 + wr * 64 + rt * 32 + rr;
        out[(size_t)m * 256 + n] = acc[rt][ct][r] + bias;
      }
    }
  }
}

// -------------------------------------------------------------- hidden ------
// hidden = tanh([h_f|h_b] @ Whid.T + bhid) ; 64x512 @ 512x256
__global__ __launch_bounds__(256) void hidden_k(
    const unsigned short* __restrict__ hfin, const unsigned short* __restrict__ whidbf,
    const float* __restrict__ bhid, float* __restrict__ out) {
  __shared__ char Ab[64 * 1024];   // [64][512] bf16, swizzled
  const int tid = threadIdx.x;
  const int w = tid >> 6, l = tid & 63;
  const int l31 = l & 31, l5 = l >> 5;

#pragma unroll
  for (int i = 0; i < 16; ++i) {
    int cc = i * 256 + tid; int row = cc >> 6, c16 = cc & 63;
    int k = c16 * 8; int dsel = k >= 256;
    uint4 v = *(const uint4*)(hfin + dsel * 16384 + row * 256 + (k & 255));
    *(uint4*)(Ab + row * 1024 + ((c16 * 16) ^ ((row & 7) << 4))) = v;
  }
  __syncthreads();

  f32x16 acc[2][2] = {};
#pragma unroll 4
  for (int kb = 0; kb < 32; ++kb) {
    const int kby = kb * 32 + l5 * 16;
    bf16x8 Af[2], Bf[2];
#pragma unroll
    for (int rt = 0; rt < 2; ++rt) {
      int row = rt * 32 + l31;
      Af[rt] = *(const bf16x8*)(Ab + row * 1024 + (kby ^ ((row & 7) << 4)));
    }
#pragma unroll
    for (int ct = 0; ct < 2; ++ct) {
      int n = w * 64 + ct * 32 + l31;
      U16x8 u; u.u4 = *(const uint4*)(whidbf + (size_t)n * 512 + kb * 16 + l5 * 8);
      Bf[ct] = u.b;
    }
#pragma unroll
    for (int rt = 0; rt < 2; ++rt)
#pragma unroll
      for (int ct = 0; ct < 2; ++ct)
        acc[rt][ct] = __builtin_amdgcn_mfma_f32_32x32x16_bf16(Af[rt], Bf[ct], acc[rt][ct], 0, 0, 0);
  }

#pragma unroll
  for (int ct = 0; ct < 2; ++ct) {
    const int n = w * 64 + ct * 32 + l31;
    const float bias = bhid[n];
#pragma unroll
    for (int rt = 0; rt < 2; ++rt) {
#pragma unroll
      for (int r = 0; r < 16; ++r) {
        const int rr = (r & 3) + 8 * (r >> 2) + 4 * l5;
        const int b = rt * 32 + rr;
        out[8388608 + (size_t)b * 256 + n] = tanh_fast(acc[rt][ct][r] + bias);
      }
    }
  }
}

// --------------------------------------------------------------- launch -----
extern "C" void kernel_launch(void* const* d_in, const int* in_sizes, int n_in,
                              void* d_out, int out_size, void* d_ws, size_t ws_size,
                              hipStream_t stream) {
  const float* src   = (const float*)d_in[0];
  const float* wih_f = (const float*)d_in[1];
  const float* whh_f = (const float*)d_in[2];
  const float* bih_f = (const float*)d_in[3];
  const float* bhh_f = (const float*)d_in[4];
  const float* wih_b = (const float*)d_in[5];
  const float* whh_b = (const float*)d_in[6];
  const float* bih_b = (const float*)d_in[7];
  const float* bhh_b = (const float*)d_in[8];
  const float* wout  = (const float*)d_in[9];
  const float* bout  = (const float*)d_in[10];
  const float* whid  = (const float*)d_in[11];
  const float* bhid  = (const float*)d_in[12];

  unsigned short* ws     = (unsigned short*)d_ws;
  unsigned short* gx     = ws + WS_GX;
  unsigned short* outw   = ws + WS_OUT;
  unsigned short* wihbf  = ws + WS_WIH;
  unsigned short* whhbf  = ws + WS_WHH;
  unsigned short* woutbf = ws + WS_WOUT;
  unsigned short* whidbf = ws + WS_WHID;
  unsigned short* hfin   = ws + WS_HFIN;
  float* out = (float*)d_out;

  prep_cvt<<<2176, 256, 0, stream>>>(wih_f, wih_b, whh_f, whh_b, wout, whid,
                                     wihbf, whhbf, woutbf, whidbf);
  gemm_gx<<<1536, 512, 0, stream>>>(src, wihbf, bih_f, bih_b, gx);
  recur<<<8, 512, 0, stream>>>(whhbf, bhh_f, bhh_b, gx, outw, hfin);
  gemm_out<<<dim3(256, 2), 256, 0, stream>>>(outw, woutbf, bout, out);
  hidden_k<<<1, 256, 0, stream>>>(hfin, whidbf, bhid, out);
}

// Round 3
// 2358.625 us; speedup vs baseline: 1.0600x; 1.0600x over previous
//
#include <hip/hip_runtime.h>

// ---------------------------------------------------------------------------
// Bidirectional GRU encoder, MI355X (gfx950)
//   src (512,64,1024) f32 -> outputs (512,64,256) f32, hidden (1,64,256) f32
//   prep    : convert weights to bf16
//   gemm_gx : gx[d] = src @ Wih_d.T + bih_d   (bf16 MFMA, 128x256 tiles)
//   recur   : 8 WGs (2 dir x 4 batch-slices of 16 rows). Whh persistent in
//             regs (192/wave). Per step: prefetch tile s+1 (global_load_lds,
//             pre-swizzled source) -> MFMA -> gates -> lgkmcnt(0)+vmcnt(8)
//             -> raw s_barrier.  vmcnt waits BEFORE the barrier so all waves'
//             tile-(s+1) loads are landed when anyone reads them (m201 rule).
//   gemm_out: outputs = [out_f|out_b] @ Wout.T + bout
//   hidden_k: hidden = tanh([h_f|h_b] @ Whid.T + bhid)
// ---------------------------------------------------------------------------

typedef short    bf16x8 __attribute__((ext_vector_type(8)));   // 8 bf16 = 4 VGPR
typedef float    f32x4  __attribute__((ext_vector_type(4)));
typedef float    f32x16 __attribute__((ext_vector_type(16)));

union U16x8 { uint4 u4; bf16x8 b; };

__device__ __forceinline__ unsigned short f2bf(float f) {
  unsigned int u = __builtin_bit_cast(unsigned int, f);
  u += 0x7fffu + ((u >> 16) & 1u);           // RNE
  return (unsigned short)(u >> 16);
}
__device__ __forceinline__ float bf2f(unsigned short h) {
  unsigned int u = ((unsigned int)h) << 16;
  return __builtin_bit_cast(float, u);
}
__device__ __forceinline__ float fast_rcp(float x) { return __builtin_amdgcn_rcpf(x); }
__device__ __forceinline__ float sigf(float x) { return fast_rcp(1.f + __expf(-x)); }
__device__ __forceinline__ float tanh_fast(float x) {
  float e = __expf(2.f * x);
  return 1.f - 2.f * fast_rcp(e + 1.f);
}

__device__ __forceinline__ void gl_lds16(const char* g, char* l) {
  __builtin_amdgcn_global_load_lds(
      (const __attribute__((address_space(1))) unsigned int*)g,
      (__attribute__((address_space(3))) unsigned int*)l, 16, 0, 0);
}

// ws element (u16) offsets
#define WS_GX      ((size_t)0)          // 2 * 512*64*768 = 50331648
#define WS_OUT     ((size_t)50331648)   // 2 * 512*64*256 = 16777216
#define WS_WIH     ((size_t)67108864)   // 2 * 768*1024   = 1572864
#define WS_WHH     ((size_t)68681728)   // 2 * 768*256    = 393216
#define WS_WOUT    ((size_t)69074944)   // 256*512        = 131072
#define WS_WHID    ((size_t)69206016)   // 256*512        = 131072
#define WS_HFIN    ((size_t)69337088)   // 2 * 64*256     = 32768

// ---------------------------------------------------------------- prep ------
__global__ void prep_cvt(const float* __restrict__ wih_f, const float* __restrict__ wih_b,
                         const float* __restrict__ whh_f, const float* __restrict__ whh_b,
                         const float* __restrict__ wout,  const float* __restrict__ whid,
                         unsigned short* __restrict__ dwih, unsigned short* __restrict__ dwhh,
                         unsigned short* __restrict__ dwout, unsigned short* __restrict__ dwhid) {
  int i4 = blockIdx.x * 256 + threadIdx.x;   // one float4 each; grid exact
  const float* s; unsigned short* d;
  if      (i4 < 196608) { s = wih_f; d = dwih; }
  else if (i4 < 393216) { s = wih_b; d = dwih + 786432; i4 -= 196608; }
  else if (i4 < 442368) { s = whh_f; d = dwhh;          i4 -= 393216; }
  else if (i4 < 491520) { s = whh_b; d = dwhh + 196608; i4 -= 442368; }
  else if (i4 < 524288) { s = wout;  d = dwout;         i4 -= 491520; }
  else                  { s = whid;  d = dwhid;         i4 -= 524288; }
  float4 v = ((const float4*)s)[i4];
  ushort4 o; o.x = f2bf(v.x); o.y = f2bf(v.y); o.z = f2bf(v.z); o.w = f2bf(v.w);
  ((ushort4*)d)[i4] = o;
}

// -------------------------------------------------------------- gx GEMM -----
__global__ __launch_bounds__(512) void gemm_gx(
    const float* __restrict__ src, const unsigned short* __restrict__ wihbf,
    const float* __restrict__ bih_f, const float* __restrict__ bih_b,
    unsigned short* __restrict__ gx) {
  __shared__ char Ab[128 * 128];   // [128 rows][64 k] bf16, swizzled
  __shared__ char Bb[256 * 128];   // [256 n  ][64 k] bf16, swizzled

  const int bx = blockIdx.x;                  // 1536
  const int xcd = bx & 7, chunk = bx >> 3;    // XCD-contiguous mtile ownership
  const int mtile = xcd * 32 + chunk / 6;
  const int ntile = chunk % 6;

  const int tid = threadIdx.x;
  const int w = tid >> 6, l = tid & 63;
  const int l31 = l & 31, l5 = l >> 5;
  const int wr = w >> 2, wc = w & 3;

  f32x16 acc[2][2] = {};

  for (int ks = 0; ks < 16; ++ks) {
#pragma unroll
    for (int i = 0; i < 4; ++i) {
      int cc = i * 512 + tid; int row = cc >> 4, c4 = cc & 15;
      float4 v = *(const float4*)(src + (size_t)(mtile * 128 + row) * 1024 + ks * 64 + c4 * 4);
      ushort4 o; o.x = f2bf(v.x); o.y = f2bf(v.y); o.z = f2bf(v.z); o.w = f2bf(v.w);
      *(ushort4*)(Ab + row * 128 + ((c4 * 8) ^ ((row & 7) << 4))) = o;
    }
#pragma unroll
    for (int i = 0; i < 4; ++i) {
      int cc = i * 512 + tid; int row = cc >> 3, c8 = cc & 7;
      uint4 v = *(const uint4*)(wihbf + (size_t)(ntile * 256 + row) * 1024 + ks * 64 + c8 * 8);
      *(uint4*)(Bb + row * 128 + ((c8 * 16) ^ ((row & 7) << 4))) = v;
    }
    __syncthreads();
#pragma unroll
    for (int kb = 0; kb < 4; ++kb) {
      const int kby = kb * 32 + l5 * 16;
      bf16x8 Af[2], Bf[2];
#pragma unroll
      for (int rt = 0; rt < 2; ++rt) {
        int row = wr * 64 + rt * 32 + l31;
        Af[rt] = *(const bf16x8*)(Ab + row * 128 + (kby ^ ((row & 7) << 4)));
      }
#pragma unroll
      for (int ct = 0; ct < 2; ++ct) {
        int nn = wc * 64 + ct * 32 + l31;
        Bf[ct] = *(const bf16x8*)(Bb + nn * 128 + (kby ^ ((nn & 7) << 4)));
      }
#pragma unroll
      for (int rt = 0; rt < 2; ++rt)
#pragma unroll
        for (int ct = 0; ct < 2; ++ct)
          acc[rt][ct] = __builtin_amdgcn_mfma_f32_32x32x16_bf16(Af[rt], Bf[ct], acc[rt][ct], 0, 0, 0);
    }
    __syncthreads();
  }

  const int cgbase = ntile * 256;
  const int d = cgbase >= 768;
  const float* bih = d ? bih_b : bih_f;
#pragma unroll
  for (int ct = 0; ct < 2; ++ct) {
    const int cg = cgbase + wc * 64 + ct * 32 + l31;
    const int c = cg - d * 768;
    const float bias = bih[c];
#pragma unroll
    for (int rt = 0; rt < 2; ++rt) {
#pragma unroll
      for (int r = 0; r < 16; ++r) {
        const int rr = (r & 3) + 8 * (r >> 2) + 4 * l5;
        const int m = mtile * 128 + wr * 64 + rt * 32 + rr;
        gx[(size_t)d * 25165824 + (size_t)m * 768 + c] = f2bf(acc[rt][ct][r] + bias);
      }
    }
  }
}

// ------------------------------------------------------------- recurrence ---
// 8 WGs: d = blk>>2, batch slice = (blk&3)*16. 8 waves; wave w owns gate
// columns [32w, 32w+32). Whh bf16 fragments persistent in regs (192/wave).
__global__ __launch_bounds__(512, 2) void recur(
    const unsigned short* __restrict__ whhbf,
    const float* __restrict__ bhh_f, const float* __restrict__ bhh_b,
    const unsigned short* __restrict__ gx,
    unsigned short* __restrict__ outw,
    unsigned short* __restrict__ hfin) {
  __shared__ char hbuf[2][8192];      // [16 rows][256 cols] bf16, XOR (row<<4)
  __shared__ char gxbuf[2][24576];    // [16 rows][768 cols] bf16, XOR ((r>>2)&3)<<5

  const int tid = threadIdx.x;
  const int w = tid >> 6, l = tid & 63;
  const int l15 = l & 15, l4 = l >> 4;
  const int d = blockIdx.x >> 2;
  const int bsl = (blockIdx.x & 3) << 4;
  const float* bhh = d ? bhh_b : bhh_f;

  // persistent weight fragments: B[k][n] = Whh[n][k]
  bf16x8 Bw[6][8];
  float bhhv[6];
#pragma unroll
  for (int j = 0; j < 6; ++j) {
    const int g = j >> 1, jt = j & 1;
    const int n = g * 256 + w * 32 + jt * 16 + l15;
    bhhv[j] = bhh[n];
#pragma unroll
    for (int kb = 0; kb < 8; ++kb) {
      const int kel = kb * 32 + l4 * 8;
      U16x8 u;
      u.u4 = *(const uint4*)(whhbf + (size_t)d * 196608 + (size_t)n * 256 + kel);
      Bw[j][kb] = u.b;
    }
  }

  float hown[2][4] = {{0.f, 0.f, 0.f, 0.f}, {0.f, 0.f, 0.f, 0.f}};

  // per-lane pre-swizzled global source byte offsets for the 3 LDS chunks
  // (linear LDS addr a -> global row pr = a/1536, col (a%1536) ^ swz(pr))
  int gofs[3];
#pragma unroll
  for (int i = 0; i < 3; ++i) {
    const int a  = i * 8192 + w * 1024 + l * 16;   // linear LDS byte addr
    const int pr = a / 1536;
    const int pc = (a % 1536) ^ (((pr >> 2) & 3) << 5);
    gofs[i] = pr * 1536 + pc;
  }

  // gate-read bases: addr = bq[jt] + (q*1536 + g*512) imm
  const int colb0 = (w * 32 + l15) * 2;
  const int bq0 = l4 * 6144 + (colb0 ^ (l4 << 5));
  const int bq1 = l4 * 6144 + ((colb0 + 32) ^ (l4 << 5));
  // out store base: +(q*512 + jt*32) imm
  const int ob = l4 * 2048 + w * 64 + l15 * 2;

  // byte strides: one time-step of gx = 64*768*2 = 98304 B; of out = 32768 B
  const int gxstep  = d ? -98304 : 98304;
  const int outstep = d ? -32768 : 32768;
  const char* gxsrc = (const char*)(gx + (size_t)d * 25165824 + (size_t)bsl * 768)
                      + (d ? (size_t)511 * 98304 : 0);
  char* outp = (char*)(outw + (size_t)d * 8388608 + (size_t)bsl * 256)
               + (d ? (size_t)511 * 32768 : 0);

  // prologue: tile 0 -> gxbuf[0]; h0 = 0; single clean drain
  {
    uint4 zz; zz.x = 0u; zz.y = 0u; zz.z = 0u; zz.w = 0u;
    *(uint4*)(hbuf[0] + tid * 16) = zz;
  }
#pragma unroll
  for (int i = 0; i < 3; ++i)
    gl_lds16(gxsrc + gofs[i], gxbuf[0] + i * 8192 + w * 1024);
  asm volatile("s_waitcnt vmcnt(0)" ::: "memory");
  __syncthreads();
  gxsrc += gxstep;   // now points at tile 1

  for (int s = 0; s < 512; ++s) {
    const int cur = s & 1;

    // 1) prefetch tile s+1 into gxbuf[cur^1]
#pragma unroll
    for (int i = 0; i < 3; ++i)
      gl_lds16(gxsrc + gofs[i], gxbuf[cur ^ 1] + i * 8192 + w * 1024);
    if (s < 510) gxsrc += gxstep;

    // 2) gh = h @ Whh.T  (A from LDS, B persistent)
    f32x4 acc[6];
#pragma unroll
    for (int j = 0; j < 6; ++j) {
      acc[j][0] = bhhv[j]; acc[j][1] = bhhv[j]; acc[j][2] = bhhv[j]; acc[j][3] = bhhv[j];
    }
    {
      const char* hb = hbuf[cur];
      const int rsw = l15 << 4;
      const int rbase = l15 * 512;
      __builtin_amdgcn_s_setprio(1);
#pragma unroll
      for (int kb = 0; kb < 8; ++kb) {
        bf16x8 Af = *(const bf16x8*)(hb + rbase + ((kb * 64 + l4 * 16) ^ rsw));
#pragma unroll
        for (int j = 0; j < 6; ++j)
          acc[j] = __builtin_amdgcn_mfma_f32_16x16x32_bf16(Af, Bw[j][kb], acc[j], 0, 0, 0);
      }
      __builtin_amdgcn_s_setprio(0);
    }

    // 3) gates: tile s in gxbuf[cur] is guaranteed (prev step's vmcnt+barrier)
    const char* gb = gxbuf[cur];
    char* hbn = hbuf[cur ^ 1];
#pragma unroll
    for (int jt = 0; jt < 2; ++jt) {
      const int bq = jt ? bq1 : bq0;
      const int colb2 = colb0 + jt * 32;
#pragma unroll
      for (int q = 0; q < 4; ++q) {
        const char* base = gb + bq + q * 1536;
        const float gxr = bf2f(*(const unsigned short*)(base));
        const float gxz = bf2f(*(const unsigned short*)(base + 512));
        const float gxn = bf2f(*(const unsigned short*)(base + 1024));
        const float rg = sigf(gxr + acc[jt][q]);
        const float zg = sigf(gxz + acc[2 + jt][q]);
        const float ng = tanh_fast(gxn + rg * acc[4 + jt][q]);
        const float hn = ng + zg * (hown[jt][q] - ng);
        hown[jt][q] = hn;
        const unsigned short h16 = f2bf(hn);
        const int row = l4 * 4 + q;
        *(unsigned short*)(hbn + row * 512 + (colb2 ^ (row << 4))) = h16;
        *(unsigned short*)(outp + ob + q * 512 + jt * 32) = h16;   // fire & forget
      }
    }
    outp += outstep;

    // 4) own h-writes visible; own prefetch landed; then barrier.
    //    vmcnt(8): per-step VMEM order = 3 loads then 8 stores; everything
    //    older was drained at the previous step's wait, so "<=8 outstanding"
    //    == this step's 8 stores -> this step's 3 loads have landed.
    asm volatile("s_waitcnt lgkmcnt(0)" ::: "memory");
    asm volatile("s_waitcnt vmcnt(8)" ::: "memory");
    __builtin_amdgcn_s_barrier();
    asm volatile("" ::: "memory");
  }

#pragma unroll
  for (int jt = 0; jt < 2; ++jt) {
    const int col = w * 32 + jt * 16 + l15;
#pragma unroll
    for (int q = 0; q < 4; ++q) {
      const int row = l4 * 4 + q;
      hfin[(size_t)d * 16384 + (size_t)(bsl + row) * 256 + col] = f2bf(hown[jt][q]);
    }
  }
}

// ------------------------------------------------------------ out proj ------
__global__ __launch_bounds__(256) void gemm_out(
    const unsigned short* __restrict__ outws, const unsigned short* __restrict__ woutbf,
    const float* __restrict__ bout, float* __restrict__ out) {
  __shared__ char Ab[128 * 128];
  __shared__ char Bb[128 * 128];
  const int mtile = blockIdx.x, ntile = blockIdx.y;
  const int tid = threadIdx.x;
  const int w = tid >> 6, l = tid & 63;
  const int l31 = l & 31, l5 = l >> 5;
  const int wr = w >> 1, wc = w & 1;

  f32x16 acc[2][2] = {};

  for (int ks = 0; ks < 8; ++ks) {
    const unsigned short* asrc = outws + (size_t)(ks >> 2) * 8388608;
    const int k0 = (ks & 3) * 64;
#pragma unroll
    for (int i = 0; i < 4; ++i) {
      int cc = i * 256 + tid; int row = cc >> 3, c8 = cc & 7;
      uint4 v = *(const uint4*)(asrc + (size_t)(mtile * 128 + row) * 256 + k0 + c8 * 8);
      *(uint4*)(Ab + row * 128 + ((c8 * 16) ^ ((row & 7) << 4))) = v;
    }
#pragma unroll
    for (int i = 0; i < 4; ++i) {
      int cc = i * 256 + tid; int row = cc >> 3, c8 = cc & 7;
      uint4 v = *(const uint4*)(woutbf + (size_t)(ntile * 128 + row) * 512 + ks * 64 + c8 * 8);
      *(uint4*)(Bb + row * 128 + ((c8 * 16) ^ ((row & 7) << 4))) = v;
    }
    __syncthreads();
#pragma unroll
    for (int kb = 0; kb < 4; ++kb) {
      const int kby = kb * 32 + l5 * 16;
      bf16x8 Af[2], Bf[2];
#pragma unroll
      for (int rt = 0; rt < 2; ++rt) {
        int row = wr * 64 + rt * 32 + l31;
        Af[rt] = *(const bf16x8*)(Ab + row * 128 + (kby ^ ((row & 7) << 4)));
      }
#pragma unroll
      for (int ct = 0; ct < 2; ++ct) {
        int nn = wc * 64 + ct * 32 + l31;
        Bf[ct] = *(const bf16x8*)(Bb + nn * 128 + (kby ^ ((nn & 7) << 4)));
      }
#pragma unroll
      for (int rt = 0; rt < 2; ++rt)
#pragma unroll
        for (int ct = 0; ct < 2; ++ct)
          acc[rt][ct] = __builtin_amdgcn_mfma_f32_32x32x16_bf16(Af[rt], Bf[ct], acc[rt][ct], 0, 0, 0);
    }
    __syncthreads();
  }

#pragma unroll
  for (int ct = 0; ct < 2; ++ct) {
    const int n = ntile * 128 + wc * 64 + ct * 32 + l31;
    const float bias = bout[n];
#pragma unroll
    for (int rt = 0; rt < 2; ++rt) {
#pragma unroll
      for (int r = 0; r < 16; ++r) {
        const int rr = (r & 3) + 8 * (r >> 2) + 4 * l5;
        const int m = mtile * 128 + wr * 64 + rt * 32 + rr;
        out[(size_t)m * 256 + n] = acc[rt][ct][r] + bias;
      }
    }
  }
}

// -------------------------------------------------------------- hidden ------
__global__ __launch_bounds__(256) void hidden_k(
    const unsigned short* __restrict__ hfin, const unsigned short* __restrict__ whidbf,
    const float* __restrict__ bhid, float* __restrict__ out) {
  __shared__ char Ab[64 * 1024];   // [64][512] bf16, swizzled
  const int tid = threadIdx.x;
  const int w = tid >> 6, l = tid & 63;
  const int l31 = l & 31, l5 = l >> 5;

#pragma unroll
  for (int i = 0; i < 16; ++i) {
    int cc = i * 256 + tid; int row = cc >> 6, c16 = cc & 63;
    int k = c16 * 8; int dsel = k >= 256;
    uint4 v = *(const uint4*)(hfin + dsel * 16384 + row * 256 + (k & 255));
    *(uint4*)(Ab + row * 1024 + ((c16 * 16) ^ ((row & 7) << 4))) = v;
  }
  __syncthreads();

  f32x16 acc[2][2] = {};
#pragma unroll 4
  for (int kb = 0; kb < 32; ++kb) {
    const int kby = kb * 32 + l5 * 16;
    bf16x8 Af[2], Bf[2];
#pragma unroll
    for (int rt = 0; rt < 2; ++rt) {
      int row = rt * 32 + l31;
      Af[rt] = *(const bf16x8*)(Ab + row * 1024 + (kby ^ ((row & 7) << 4)));
    }
#pragma unroll
    for (int ct = 0; ct < 2; ++ct) {
      int n = w * 64 + ct * 32 + l31;
      U16x8 u; u.u4 = *(const uint4*)(whidbf + (size_t)n * 512 + kb * 16 + l5 * 8);
      Bf[ct] = u.b;
    }
#pragma unroll
    for (int rt = 0; rt < 2; ++rt)
#pragma unroll
      for (int ct = 0; ct < 2; ++ct)
        acc[rt][ct] = __builtin_amdgcn_mfma_f32_32x32x16_bf16(Af[rt], Bf[ct], acc[rt][ct], 0, 0, 0);
  }

#pragma unroll
  for (int ct = 0; ct < 2; ++ct) {
    const int n = w * 64 + ct * 32 + l31;
    const float bias = bhid[n];
#pragma unroll
    for (int rt = 0; rt < 2; ++rt) {
#pragma unroll
      for (int r = 0; r < 16; ++r) {
        const int rr = (r & 3) + 8 * (r >> 2) + 4 * l5;
        const int b = rt * 32 + rr;
        out[8388608 + (size_t)b * 256 + n] = tanh_fast(acc[rt][ct][r] + bias);
      }
    }
  }
}

// --------------------------------------------------------------- launch -----
extern "C" void kernel_launch(void* const* d_in, const int* in_sizes, int n_in,
                              void* d_out, int out_size, void* d_ws, size_t ws_size,
                              hipStream_t stream) {
  const float* src   = (const float*)d_in[0];
  const float* wih_f = (const float*)d_in[1];
  const float* whh_f = (const float*)d_in[2];
  const float* bih_f = (const float*)d_in[3];
  const float* bhh_f = (const float*)d_in[4];
  const float* wih_b = (const float*)d_in[5];
  const float* whh_b = (const float*)d_in[6];
  const float* bih_b = (const float*)d_in[7];
  const float* bhh_b = (const float*)d_in[8];
  const float* wout  = (const float*)d_in[9];
  const float* bout  = (const float*)d_in[10];
  const float* whid  = (const float*)d_in[11];
  const float* bhid  = (const float*)d_in[12];

  unsigned short* ws     = (unsigned short*)d_ws;
  unsigned short* gx     = ws + WS_GX;
  unsigned short* outw   = ws + WS_OUT;
  unsigned short* wihbf  = ws + WS_WIH;
  unsigned short* whhbf  = ws + WS_WHH;
  unsigned short* woutbf = ws + WS_WOUT;
  unsigned short* whidbf = ws + WS_WHID;
  unsigned short* hfin   = ws + WS_HFIN;
  float* out = (float*)d_out;

  prep_cvt<<<2176, 256, 0, stream>>>(wih_f, wih_b, whh_f, whh_b, wout, whid,
                                     wihbf, whhbf, woutbf, whidbf);
  gemm_gx<<<1536, 512, 0, stream>>>(src, wihbf, bih_f, bih_b, gx);
  recur<<<8, 512, 0, stream>>>(whhbf, bhh_f, bhh_b, gx, outw, hfin);
  gemm_out<<<dim3(256, 2), 256, 0, stream>>>(outw, woutbf, bout, out);
  hidden_k<<<1, 256, 0, stream>>>(hfin, whidbf, bhid, out);
}

// Round 4
// 1699.680 us; speedup vs baseline: 1.4709x; 1.3877x over previous
//
#include <hip/hip_runtime.h>

// ---------------------------------------------------------------------------
// Bidirectional GRU encoder, MI355X (gfx950)
//   src (512,64,1024) f32 -> outputs (512,64,256) f32, hidden (1,64,256) f32
//   prep    : convert weights to bf16
//   gemm_gx : gx[d] = src @ Wih_d.T + (bih_d + [bhh_d for r,z])
//   recur   : 8 WGs (2 dir x 4 batch-slices of 16 rows). TRANSPOSED gates:
//             ghT = Whh @ hT via swapped MFMA operands, so each lane owns 4
//             consecutive h-cols of one batch row -> b64 LDS/global accesses.
//   gemm_out: outputs = [out_f|out_b] @ Wout.T + bout
//   hidden_k: hidden = tanh([h_f|h_b] @ Whid.T + bhid)
// ---------------------------------------------------------------------------

typedef short    bf16x8 __attribute__((ext_vector_type(8)));   // 8 bf16 = 4 VGPR
typedef float    f32x4  __attribute__((ext_vector_type(4)));
typedef float    f32x16 __attribute__((ext_vector_type(16)));

union U16x8 { uint4 u4; bf16x8 b; };

__device__ __forceinline__ unsigned short f2bf(float f) {
  unsigned int u = __builtin_bit_cast(unsigned int, f);
  u += 0x7fffu + ((u >> 16) & 1u);           // RNE
  return (unsigned short)(u >> 16);
}
__device__ __forceinline__ float bf2f_lo(unsigned int u) {   // low u16 -> f32
  return __builtin_bit_cast(float, u << 16);
}
__device__ __forceinline__ float bf2f_hi(unsigned int u) {   // high u16 -> f32
  return __builtin_bit_cast(float, u & 0xffff0000u);
}
__device__ __forceinline__ unsigned int cvt_pk_bf16(float lo, float hi) {
  unsigned int r;
  asm("v_cvt_pk_bf16_f32 %0, %1, %2" : "=v"(r) : "v"(lo), "v"(hi));
  return r;
}
__device__ __forceinline__ float fast_rcp(float x) { return __builtin_amdgcn_rcpf(x); }
__device__ __forceinline__ float sigf(float x) { return fast_rcp(1.f + __expf(-x)); }
__device__ __forceinline__ float tanh_fast(float x) {
  float e = __expf(2.f * x);
  return 1.f - 2.f * fast_rcp(e + 1.f);
}

__device__ __forceinline__ void gl_lds16(const char* g, char* l) {
  __builtin_amdgcn_global_load_lds(
      (const __attribute__((address_space(1))) unsigned int*)g,
      (__attribute__((address_space(3))) unsigned int*)l, 16, 0, 0);
}

// ws element (u16) offsets
#define WS_GX      ((size_t)0)          // 2 * 512*64*768 = 50331648
#define WS_OUT     ((size_t)50331648)   // 2 * 512*64*256 = 16777216
#define WS_WIH     ((size_t)67108864)   // 2 * 768*1024   = 1572864
#define WS_WHH     ((size_t)68681728)   // 2 * 768*256    = 393216
#define WS_WOUT    ((size_t)69074944)   // 256*512        = 131072
#define WS_WHID    ((size_t)69206016)   // 256*512        = 131072
#define WS_HFIN    ((size_t)69337088)   // 2 * 64*256     = 32768

// ---------------------------------------------------------------- prep ------
__global__ void prep_cvt(const float* __restrict__ wih_f, const float* __restrict__ wih_b,
                         const float* __restrict__ whh_f, const float* __restrict__ whh_b,
                         const float* __restrict__ wout,  const float* __restrict__ whid,
                         unsigned short* __restrict__ dwih, unsigned short* __restrict__ dwhh,
                         unsigned short* __restrict__ dwout, unsigned short* __restrict__ dwhid) {
  int i4 = blockIdx.x * 256 + threadIdx.x;   // one float4 each; grid exact
  const float* s; unsigned short* d;
  if      (i4 < 196608) { s = wih_f; d = dwih; }
  else if (i4 < 393216) { s = wih_b; d = dwih + 786432; i4 -= 196608; }
  else if (i4 < 442368) { s = whh_f; d = dwhh;          i4 -= 393216; }
  else if (i4 < 491520) { s = whh_b; d = dwhh + 196608; i4 -= 442368; }
  else if (i4 < 524288) { s = wout;  d = dwout;         i4 -= 491520; }
  else                  { s = whid;  d = dwhid;         i4 -= 524288; }
  float4 v = ((const float4*)s)[i4];
  ushort4 o; o.x = f2bf(v.x); o.y = f2bf(v.y); o.z = f2bf(v.z); o.w = f2bf(v.w);
  ((ushort4*)d)[i4] = o;
}

// -------------------------------------------------------------- gx GEMM -----
__global__ __launch_bounds__(512) void gemm_gx(
    const float* __restrict__ src, const unsigned short* __restrict__ wihbf,
    const float* __restrict__ bih_f, const float* __restrict__ bih_b,
    const float* __restrict__ bhh_f, const float* __restrict__ bhh_b,
    unsigned short* __restrict__ gx) {
  __shared__ char Ab[128 * 128];   // [128 rows][64 k] bf16, swizzled
  __shared__ char Bb[256 * 128];   // [256 n  ][64 k] bf16, swizzled

  const int bx = blockIdx.x;                  // 1536
  const int xcd = bx & 7, chunk = bx >> 3;    // XCD-contiguous mtile ownership
  const int mtile = xcd * 32 + chunk / 6;
  const int ntile = chunk % 6;

  const int tid = threadIdx.x;
  const int w = tid >> 6, l = tid & 63;
  const int l31 = l & 31, l5 = l >> 5;
  const int wr = w >> 2, wc = w & 3;

  f32x16 acc[2][2] = {};

  for (int ks = 0; ks < 16; ++ks) {
#pragma unroll
    for (int i = 0; i < 4; ++i) {
      int cc = i * 512 + tid; int row = cc >> 4, c4 = cc & 15;
      float4 v = *(const float4*)(src + (size_t)(mtile * 128 + row) * 1024 + ks * 64 + c4 * 4);
      ushort4 o; o.x = f2bf(v.x); o.y = f2bf(v.y); o.z = f2bf(v.z); o.w = f2bf(v.w);
      *(ushort4*)(Ab + row * 128 + ((c4 * 8) ^ ((row & 7) << 4))) = o;
    }
#pragma unroll
    for (int i = 0; i < 4; ++i) {
      int cc = i * 512 + tid; int row = cc >> 3, c8 = cc & 7;
      uint4 v = *(const uint4*)(wihbf + (size_t)(ntile * 256 + row) * 1024 + ks * 64 + c8 * 8);
      *(uint4*)(Bb + row * 128 + ((c8 * 16) ^ ((row & 7) << 4))) = v;
    }
    __syncthreads();
#pragma unroll
    for (int kb = 0; kb < 4; ++kb) {
      const int kby = kb * 32 + l5 * 16;
      bf16x8 Af[2], Bf[2];
#pragma unroll
      for (int rt = 0; rt < 2; ++rt) {
        int row = wr * 64 + rt * 32 + l31;
        Af[rt] = *(const bf16x8*)(Ab + row * 128 + (kby ^ ((row & 7) << 4)));
      }
#pragma unroll
      for (int ct = 0; ct < 2; ++ct) {
        int nn = wc * 64 + ct * 32 + l31;
        Bf[ct] = *(const bf16x8*)(Bb + nn * 128 + (kby ^ ((nn & 7) << 4)));
      }
#pragma unroll
      for (int rt = 0; rt < 2; ++rt)
#pragma unroll
        for (int ct = 0; ct < 2; ++ct)
          acc[rt][ct] = __builtin_amdgcn_mfma_f32_32x32x16_bf16(Af[rt], Bf[ct], acc[rt][ct], 0, 0, 0);
    }
    __syncthreads();
  }

  const int cgbase = ntile * 256;
  const int d = cgbase >= 768;
  const float* bih = d ? bih_b : bih_f;
  const float* bhh = d ? bhh_b : bhh_f;
#pragma unroll
  for (int ct = 0; ct < 2; ++ct) {
    const int cg = cgbase + wc * 64 + ct * 32 + l31;
    const int c = cg - d * 768;
    // fold bhh into gx for r,z gates only (n-gate bhh stays inside r-multiply)
    const float bias = bih[c] + (c < 512 ? bhh[c] : 0.f);
#pragma unroll
    for (int rt = 0; rt < 2; ++rt) {
#pragma unroll
      for (int r = 0; r < 16; ++r) {
        const int rr = (r & 3) + 8 * (r >> 2) + 4 * l5;
        const int m = mtile * 128 + wr * 64 + rt * 32 + rr;
        gx[(size_t)d * 25165824 + (size_t)m * 768 + c] = f2bf(acc[rt][ct][r] + bias);
      }
    }
  }
}

// ------------------------------------------------------------- recurrence ---
// 8 WGs: d = blk>>2, batch slice = (blk&3)*16. 8 waves; wave w owns gate
// cols [32w,32w+32) of each gate. ghT = Whh @ hT (swapped MFMA operands):
// lane holds gates for batch=l&15, hcols (l>>4)*4+q -> b64 access everywhere.
__global__ __launch_bounds__(512, 2) void recur(
    const unsigned short* __restrict__ whhbf,
    const float* __restrict__ bhh_f, const float* __restrict__ bhh_b,
    const unsigned short* __restrict__ gx,
    unsigned short* __restrict__ outw,
    unsigned short* __restrict__ hfin) {
  __shared__ char hbuf[2][8192];      // [16 rows][256 cols] bf16, XOR (row<<4)
  __shared__ char gxbuf[2][24576];    // [16 rows][768 cols] bf16, XOR (row&7)<<4

  const int tid = threadIdx.x;
  const int w = tid >> 6, l = tid & 63;
  const int l15 = l & 15, l4 = l >> 4;
  const int d = blockIdx.x >> 2;
  const int bsl = (blockIdx.x & 3) << 4;
  const float* bhh = d ? bhh_b : bhh_f;

  // persistent weight fragments (A operand): Aw[j][kb] lane l =
  //   Whh[n = g3*256 + w*32 + jt*16 + l15][k = kb*32 + l4*8 .. +7]
  bf16x8 Aw[6][8];
#pragma unroll
  for (int j = 0; j < 6; ++j) {
    const int g3 = j >> 1, jt = j & 1;
    const int n = g3 * 256 + w * 32 + jt * 16 + l15;
#pragma unroll
    for (int kb = 0; kb < 8; ++kb) {
      U16x8 u;
      u.u4 = *(const uint4*)(whhbf + (size_t)d * 196608 + (size_t)n * 256 + kb * 32 + l4 * 8);
      Aw[j][kb] = u.b;
    }
  }
  // n-gate bhh accumulator init values: bhh[512 + w*32 + jt*16 + l4*4 + q]
  float bhv[2][4];
#pragma unroll
  for (int jt = 0; jt < 2; ++jt)
#pragma unroll
    for (int q = 0; q < 4; ++q)
      bhv[jt][q] = bhh[512 + w * 32 + jt * 16 + l4 * 4 + q];

  float hown[2][4] = {{0.f, 0.f, 0.f, 0.f}, {0.f, 0.f, 0.f, 0.f}};

  // per-lane pre-swizzled global source byte offsets for the 3 LDS chunks
  int gofs[3];
#pragma unroll
  for (int i = 0; i < 3; ++i) {
    const int a  = i * 8192 + w * 1024 + l * 16;   // linear LDS byte addr
    const int pr = a / 1536;
    const int pc = (a % 1536) ^ ((pr & 7) << 4);
    gofs[i] = pr * 1536 + pc;
  }

  // gate-read base (per jt add jt*32 before XOR; jt*32 ^-safe? jt*32 touches
  // bit 5 which the swizzle also uses -> compute both bases explicitly)
  const int sw2 = (l15 & 7) << 4;
  const int bq0 = l15 * 1536 + ((w * 64 + l4 * 8) ^ sw2);
  const int bq1 = l15 * 1536 + ((w * 64 + 32 + l4 * 8) ^ sw2);
  // h-write bases (row swizzle l15<<4)
  const int hw0 = l15 * 512 + ((w * 64 + l4 * 8) ^ (l15 << 4));
  const int hw1 = l15 * 512 + ((w * 64 + 32 + l4 * 8) ^ (l15 << 4));
  // out store base: + jt*32 imm
  const int ob2 = (bsl + l15) * 512 + w * 64 + l4 * 8;

  // byte strides: one time-step of gx = 64*768*2 = 98304 B; of out = 32768 B
  const int gxstep  = d ? -98304 : 98304;
  const int outstep = d ? -32768 : 32768;
  const char* gxsrc = (const char*)(gx + (size_t)d * 25165824 + (size_t)bsl * 768)
                      + (d ? (size_t)511 * 98304 : 0);
  char* outp = (char*)(outw + (size_t)d * 8388608)
               + (d ? (size_t)511 * 32768 : 0);

  // prologue: tile 0 -> gxbuf[0]; h0 = 0; single clean drain
  {
    uint4 zz; zz.x = 0u; zz.y = 0u; zz.z = 0u; zz.w = 0u;
    *(uint4*)(hbuf[0] + tid * 16) = zz;
  }
#pragma unroll
  for (int i = 0; i < 3; ++i)
    gl_lds16(gxsrc + gofs[i], gxbuf[0] + i * 8192 + w * 1024);
  asm volatile("s_waitcnt vmcnt(0)" ::: "memory");
  __syncthreads();
  gxsrc += gxstep;   // now points at tile 1

  for (int s = 0; s < 512; ++s) {
    const int cur = s & 1;

    // 1) prefetch tile s+1 into gxbuf[cur^1]
#pragma unroll
    for (int i = 0; i < 3; ++i)
      gl_lds16(gxsrc + gofs[i], gxbuf[cur ^ 1] + i * 8192 + w * 1024);
    if (s < 510) gxsrc += gxstep;

    // 2) ghT = Whh @ hT  (A persistent weights, B = h fragment from LDS)
    f32x4 acc[6];
#pragma unroll
    for (int j = 0; j < 4; ++j) { acc[j][0] = 0.f; acc[j][1] = 0.f; acc[j][2] = 0.f; acc[j][3] = 0.f; }
#pragma unroll
    for (int jt = 0; jt < 2; ++jt) {
      acc[4 + jt][0] = bhv[jt][0]; acc[4 + jt][1] = bhv[jt][1];
      acc[4 + jt][2] = bhv[jt][2]; acc[4 + jt][3] = bhv[jt][3];
    }
    {
      const char* hb = hbuf[cur];
      const int rsw = l15 << 4;
      const int rbase = l15 * 512;
      __builtin_amdgcn_s_setprio(1);
#pragma unroll
      for (int kb = 0; kb < 8; ++kb) {
        bf16x8 Bf = *(const bf16x8*)(hb + rbase + ((kb * 64 + l4 * 16) ^ rsw));
#pragma unroll
        for (int j = 0; j < 6; ++j)
          acc[j] = __builtin_amdgcn_mfma_f32_16x16x32_bf16(Aw[j][kb], Bf, acc[j], 0, 0, 0);
      }
      __builtin_amdgcn_s_setprio(0);
    }

    // 3) gates: lane owns batch=l15, hcols w*32 + jt*16 + l4*4 + 0..3
    const char* gb = gxbuf[cur];
    char* hbn = hbuf[cur ^ 1];
#pragma unroll
    for (int jt = 0; jt < 2; ++jt) {
      const char* base = gb + (jt ? bq1 : bq0);
      const uint2 gr = *(const uint2*)(base);
      const uint2 gz = *(const uint2*)(base + 512);
      const uint2 gn = *(const uint2*)(base + 1024);
      const float gxr[4] = { bf2f_lo(gr.x), bf2f_hi(gr.x), bf2f_lo(gr.y), bf2f_hi(gr.y) };
      const float gxz[4] = { bf2f_lo(gz.x), bf2f_hi(gz.x), bf2f_lo(gz.y), bf2f_hi(gz.y) };
      const float gxn[4] = { bf2f_lo(gn.x), bf2f_hi(gn.x), bf2f_lo(gn.y), bf2f_hi(gn.y) };
      float hv[4];
#pragma unroll
      for (int q = 0; q < 4; ++q) {
        const float rg = sigf(gxr[q] + acc[jt][q]);
        const float zg = sigf(gxz[q] + acc[2 + jt][q]);
        const float ng = tanh_fast(fmaf(rg, acc[4 + jt][q], gxn[q]));
        hv[q] = ng + zg * (hown[jt][q] - ng);
        hown[jt][q] = hv[q];
      }
      uint2 P;
      P.x = cvt_pk_bf16(hv[0], hv[1]);
      P.y = cvt_pk_bf16(hv[2], hv[3]);
      *(uint2*)(hbn + (jt ? hw1 : hw0)) = P;                      // h for next step
      *(uint2*)(outp + ob2 + jt * 32) = P;                        // fire & forget
    }
    outp += outstep;

    // 4) own h-writes visible; own prefetch landed; then barrier.
    //    vmcnt(2): per-step VMEM order = 3 loads then 2 stores; <=2
    //    outstanding == this step's stores -> the 3 loads have landed.
    asm volatile("s_waitcnt lgkmcnt(0)" ::: "memory");
    asm volatile("s_waitcnt vmcnt(2)" ::: "memory");
    __builtin_amdgcn_sched_barrier(0);
    __builtin_amdgcn_s_barrier();
    asm volatile("" ::: "memory");
  }

  // final hidden state
#pragma unroll
  for (int jt = 0; jt < 2; ++jt) {
    uint2 P;
    P.x = cvt_pk_bf16(hown[jt][0], hown[jt][1]);
    P.y = cvt_pk_bf16(hown[jt][2], hown[jt][3]);
    *(uint2*)(hfin + (size_t)d * 16384 + (size_t)(bsl + l15) * 256
              + w * 32 + jt * 16 + l4 * 4) = P;
  }
}

// ------------------------------------------------------------ out proj ------
__global__ __launch_bounds__(256) void gemm_out(
    const unsigned short* __restrict__ outws, const unsigned short* __restrict__ woutbf,
    const float* __restrict__ bout, float* __restrict__ out) {
  __shared__ char Ab[128 * 128];
  __shared__ char Bb[128 * 128];
  const int mtile = blockIdx.x, ntile = blockIdx.y;
  const int tid = threadIdx.x;
  const int w = tid >> 6, l = tid & 63;
  const int l31 = l & 31, l5 = l >> 5;
  const int wr = w >> 1, wc = w & 1;

  f32x16 acc[2][2] = {};

  for (int ks = 0; ks < 8; ++ks) {
    const unsigned short* asrc = outws + (size_t)(ks >> 2) * 8388608;
    const int k0 = (ks & 3) * 64;
#pragma unroll
    for (int i = 0; i < 4; ++i) {
      int cc = i * 256 + tid; int row = cc >> 3, c8 = cc & 7;
      uint4 v = *(const uint4*)(asrc + (size_t)(mtile * 128 + row) * 256 + k0 + c8 * 8);
      *(uint4*)(Ab + row * 128 + ((c8 * 16) ^ ((row & 7) << 4))) = v;
    }
#pragma unroll
    for (int i = 0; i < 4; ++i) {
      int cc = i * 256 + tid; int row = cc >> 3, c8 = cc & 7;
      uint4 v = *(const uint4*)(woutbf + (size_t)(ntile * 128 + row) * 512 + ks * 64 + c8 * 8);
      *(uint4*)(Bb + row * 128 + ((c8 * 16) ^ ((row & 7) << 4))) = v;
    }
    __syncthreads();
#pragma unroll
    for (int kb = 0; kb < 4; ++kb) {
      const int kby = kb * 32 + l5 * 16;
      bf16x8 Af[2], Bf[2];
#pragma unroll
      for (int rt = 0; rt < 2; ++rt) {
        int row = wr * 64 + rt * 32 + l31;
        Af[rt] = *(const bf16x8*)(Ab + row * 128 + (kby ^ ((row & 7) << 4)));
      }
#pragma unroll
      for (int ct = 0; ct < 2; ++ct) {
        int nn = wc * 64 + ct * 32 + l31;
        Bf[ct] = *(const bf16x8*)(Bb + nn * 128 + (kby ^ ((nn & 7) << 4)));
      }
#pragma unroll
      for (int rt = 0; rt < 2; ++rt)
#pragma unroll
        for (int ct = 0; ct < 2; ++ct)
          acc[rt][ct] = __builtin_amdgcn_mfma_f32_32x32x16_bf16(Af[rt], Bf[ct], acc[rt][ct], 0, 0, 0);
    }
    __syncthreads();
  }

#pragma unroll
  for (int ct = 0; ct < 2; ++ct) {
    const int n = ntile * 128 + wc * 64 + ct * 32 + l31;
    const float bias = bout[n];
#pragma unroll
    for (int rt = 0; rt < 2; ++rt) {
#pragma unroll
      for (int r = 0; r < 16; ++r) {
        const int rr = (r & 3) + 8 * (r >> 2) + 4 * l5;
        const int m = mtile * 128 + wr * 64 + rt * 32 + rr;
        out[(size_t)m * 256 + n] = acc[rt][ct][r] + bias;
      }
    }
  }
}

// -------------------------------------------------------------- hidden ------
__global__ __launch_bounds__(256) void hidden_k(
    const unsigned short* __restrict__ hfin, const unsigned short* __restrict__ whidbf,
    const float* __restrict__ bhid, float* __restrict__ out) {
  __shared__ char Ab[64 * 1024];   // [64][512] bf16, swizzled
  const int tid = threadIdx.x;
  const int w = tid >> 6, l = tid & 63;
  const int l31 = l & 31, l5 = l >> 5;

#pragma unroll
  for (int i = 0; i < 16; ++i) {
    int cc = i * 256 + tid; int row = cc >> 6, c16 = cc & 63;
    int k = c16 * 8; int dsel = k >= 256;
    uint4 v = *(const uint4*)(hfin + dsel * 16384 + row * 256 + (k & 255));
    *(uint4*)(Ab + row * 1024 + ((c16 * 16) ^ ((row & 7) << 4))) = v;
  }
  __syncthreads();

  f32x16 acc[2][2] = {};
#pragma unroll 4
  for (int kb = 0; kb < 32; ++kb) {
    const int kby = kb * 32 + l5 * 16;
    bf16x8 Af[2], Bf[2];
#pragma unroll
    for (int rt = 0; rt < 2; ++rt) {
      int row = rt * 32 + l31;
      Af[rt] = *(const bf16x8*)(Ab + row * 1024 + (kby ^ ((row & 7) << 4)));
    }
#pragma unroll
    for (int ct = 0; ct < 2; ++ct) {
      int n = w * 64 + ct * 32 + l31;
      U16x8 u; u.u4 = *(const uint4*)(whidbf + (size_t)n * 512 + kb * 16 + l5 * 8);
      Bf[ct] = u.b;
    }
#pragma unroll
    for (int rt = 0; rt < 2; ++rt)
#pragma unroll
      for (int ct = 0; ct < 2; ++ct)
        acc[rt][ct] = __builtin_amdgcn_mfma_f32_32x32x16_bf16(Af[rt], Bf[ct], acc[rt][ct], 0, 0, 0);
  }

#pragma unroll
  for (int ct = 0; ct < 2; ++ct) {
    const int n = w * 64 + ct * 32 + l31;
    const float bias = bhid[n];
#pragma unroll
    for (int rt = 0; rt < 2; ++rt) {
#pragma unroll
      for (int r = 0; r < 16; ++r) {
        const int rr = (r & 3) + 8 * (r >> 2) + 4 * l5;
        const int b = rt * 32 + rr;
        out[8388608 + (size_t)b * 256 + n] = tanh_fast(acc[rt][ct][r] + bias);
      }
    }
  }
}

// --------------------------------------------------------------- launch -----
extern "C" void kernel_launch(void* const* d_in, const int* in_sizes, int n_in,
                              void* d_out, int out_size, void* d_ws, size_t ws_size,
                              hipStream_t stream) {
  const float* src   = (const float*)d_in[0];
  const float* wih_f = (const float*)d_in[1];
  const float* whh_f = (const float*)d_in[2];
  const float* bih_f = (const float*)d_in[3];
  const float* bhh_f = (const float*)d_in[4];
  const float* wih_b = (const float*)d_in[5];
  const float* whh_b = (const float*)d_in[6];
  const float* bih_b = (const float*)d_in[7];
  const float* bhh_b = (const float*)d_in[8];
  const float* wout  = (const float*)d_in[9];
  const float* bout  = (const float*)d_in[10];
  const float* whid  = (const float*)d_in[11];
  const float* bhid  = (const float*)d_in[12];

  unsigned short* ws     = (unsigned short*)d_ws;
  unsigned short* gx     = ws + WS_GX;
  unsigned short* outw   = ws + WS_OUT;
  unsigned short* wihbf  = ws + WS_WIH;
  unsigned short* whhbf  = ws + WS_WHH;
  unsigned short* woutbf = ws + WS_WOUT;
  unsigned short* whidbf = ws + WS_WHID;
  unsigned short* hfin   = ws + WS_HFIN;
  float* out = (float*)d_out;

  prep_cvt<<<2176, 256, 0, stream>>>(wih_f, wih_b, whh_f, whh_b, wout, whid,
                                     wihbf, whhbf, woutbf, whidbf);
  gemm_gx<<<1536, 512, 0, stream>>>(src, wihbf, bih_f, bih_b, bhh_f, bhh_b, gx);
  recur<<<8, 512, 0, stream>>>(whhbf, bhh_f, bhh_b, gx, outw, hfin);
  gemm_out<<<dim3(256, 2), 256, 0, stream>>>(outw, woutbf, bout, out);
  hidden_k<<<1, 256, 0, stream>>>(hfin, whidbf, bhid, out);
}